// Round 7
// baseline (163.221 us; speedup 1.0000x reference)
//
#include <hip/hip_runtime.h>

#define NDIM 1024
#define CH 16
#define ROW_F4 4096   // float4 per W row (1024*16/4)

__device__ inline float4 f4add(float4 a, float4 b) {
    return make_float4(a.x + b.x, a.y + b.y, a.z + b.z, a.w + b.w);
}
__device__ inline float4 f4zero() { return make_float4(0.f, 0.f, 0.f, 0.f); }

// ---------------------------------------------------------------------------
// k_fused: ONE pass over W -> row partials (16 j-chunks), col partials
// (128 i-chunks), and per-tile totals. Block = 8 rows x 64 cols.
// LDS = 8x258 float4 (33 KB) -> 4 blocks/CU, 16 waves/CU.
// All partials live in out0 (dead scratch until k_main overwrites it).
// ---------------------------------------------------------------------------
__global__ __launch_bounds__(256) void k_fused(const float* __restrict__ W1,
                                               const float* __restrict__ W2,
                                               float* __restrict__ rowpart,
                                               float* __restrict__ colpart,
                                               float* __restrict__ tiletot) {
    int t  = threadIdx.x;
    int jt = blockIdx.x, it = blockIdx.y, z = blockIdx.z;
    const float4* base = (const float4*)(z ? W2 : W1)
                       + (size_t)it * 8 * ROW_F4 + jt * 256 + t;
    __shared__ float4 tile[8][258];   // pad 256->258: epilogue reads 2-way max
    __shared__ float4 rtot[32];
    float4 colacc = f4zero();
#pragma unroll
    for (int r = 0; r < 8; ++r) {
        float4 v = base[(size_t)r * ROW_F4];
        colacc = f4add(colacc, v);
        tile[r][t] = v;
    }
    // col partial: thread owns (j = jt*64 + (t>>2), cq = t&3); contiguous store
    ((float4*)colpart)[(size_t)(z * 128 + it) * 4096 + jt * 256 + t] = colacc;
    __syncthreads();
    if (t < 32) {   // row partials: r = t>>2, cq = t&3; sum 64 j's from LDS
        int r = t >> 2, cq = t & 3;
        float4 s = f4zero();
#pragma unroll
        for (int jl = 0; jl < 64; ++jl) s = f4add(s, tile[r][jl * 4 + cq]);
        ((float4*)rowpart)[(size_t)(z * 16 + jt) * 4096 + (it * 8 + r) * 4 + cq] = s;
        rtot[t] = s;
    }
    __syncthreads();
    if (t < 4) {    // tile total (16 ch) for global sums
        float4 s = f4zero();
#pragma unroll
        for (int r = 0; r < 8; ++r) s = f4add(s, rtot[r * 4 + t]);
        ((float4*)tiletot)[(size_t)(z * 2048 + it * 16 + jt) * 4 + t] = s;
    }
}

// ---------------------------------------------------------------------------
// k_mid: finalize + global sums + all O(N) outputs, one kernel (64 blocks).
// Block handles 16 i's. Global sums computed redundantly per block from
// tiletot (256 KB, L2). Finalized row/col sums built in LDS from partials.
//   R0[i][o] = rsW1[i]·θ0_1
//   C0[j][o] = csW1[j]·θ0_2 + rsW2[j]·θ0_4 + b1[j]·θ0_6 + const0 + bias0
//   R1[i][o] = csW1[i]·θ1_0 + rsW2[i]·θ1_3 + b1[i]·θ1_6
//   C1[j][o] = csW2[j]·θ1_4 + b2[j]·θ1_8 + const1 + bias1
//   out2/out3 with constants folded. theta [k][c][o] at k*256 + c*16 + o
// ---------------------------------------------------------------------------
__global__ __launch_bounds__(256) void k_mid(const float* __restrict__ rowpart,
                                             const float* __restrict__ colpart,
                                             const float* __restrict__ tiletot,
                                             const float* __restrict__ b1,
                                             const float* __restrict__ b2,
                                             const float* __restrict__ th0,
                                             const float* __restrict__ th1,
                                             const float* __restrict__ th2,
                                             const float* __restrict__ th3,
                                             const float* __restrict__ bias0,
                                             const float* __restrict__ bias1,
                                             const float* __restrict__ bias2,
                                             const float* __restrict__ bias3,
                                             float* __restrict__ R0, float* __restrict__ C0,
                                             float* __restrict__ R1, float* __restrict__ C1,
                                             float* __restrict__ out2, float* __restrict__ out3) {
    int t  = threadIdx.x;
    int i0 = blockIdx.x * 16;
    __shared__ float sums[64];                       // [W1|W2|b1|b2][16]
    __shared__ float Ars1[16][16], Ars2[16][16], Acs1[16][16], Acs2[16][16];

    // Step A: global sums (threads 0..63)
    if (t < 32) {
        int z = t >> 4, c = t & 15;
        float s = 0.f;
        for (int k = 0; k < 2048; ++k) s += tiletot[(size_t)(z * 2048 + k) * 16 + c];
        sums[z * 16 + c] = s;
    } else if (t < 64) {
        int w = (t - 32) >> 4, c = t & 15;
        const float* b = w ? b2 : b1;
        float s = 0.f;
        for (int k = 0; k < 1024; ++k) s += b[k * 16 + c];
        sums[32 + w * 16 + c] = s;
    }

    // Step B: finalize row/col sums for this block's 16 i's (all threads)
    {
        int il = t >> 4, c = t & 15, i = i0 + il;
        float s = 0.f;
#pragma unroll 4
        for (int k = 0; k < 16; ++k)  s += rowpart[((size_t)k * 1024 + i) * 16 + c];
        Ars1[il][c] = s;
        s = 0.f;
#pragma unroll 4
        for (int k = 0; k < 16; ++k)  s += rowpart[((size_t)(16 + k) * 1024 + i) * 16 + c];
        Ars2[il][c] = s;
        s = 0.f;
#pragma unroll 8
        for (int k = 0; k < 128; ++k) s += colpart[((size_t)k * 1024 + i) * 16 + c];
        Acs1[il][c] = s;
        s = 0.f;
#pragma unroll 8
        for (int k = 0; k < 128; ++k) s += colpart[((size_t)(128 + k) * 1024 + i) * 16 + c];
        Acs2[il][c] = s;
    }
    __syncthreads();

    // Step C: smalls math. Thread -> (il, o).
    int il = t >> 4, o = t & 15, i = i0 + il;
    const float* b1i = b1 + i * 16;
    const float* b2i = b2 + i * 16;
    float r0 = 0.f, c0a = 0.f, r1 = 0.f, c1a = 0.f, o2 = 0.f, o3 = 0.f;
    float k0 = 0.f, k1 = 0.f, k2 = 0.f, k3 = 0.f;
#pragma unroll
    for (int c = 0; c < 16; ++c) {
        float sW1 = sums[c], sW2 = sums[16 + c], sb1 = sums[32 + c], sb2 = sums[48 + c];
        float rs1 = Ars1[il][c], rs2 = Ars2[il][c];
        float cs1 = Acs1[il][c], cs2 = Acs2[il][c];
        float vb1 = b1i[c], vb2 = b2i[c];
        r0  += rs1 * th0[(1 * 16 + c) * 16 + o];
        c0a += cs1 * th0[(2 * 16 + c) * 16 + o]
             + rs2 * th0[(4 * 16 + c) * 16 + o]
             + vb1 * th0[(6 * 16 + c) * 16 + o];
        k0  += sW1 * th0[(3 * 16 + c) * 16 + o] + sW2 * th0[(5 * 16 + c) * 16 + o]
             + sb1 * th0[(7 * 16 + c) * 16 + o] + sb2 * th0[(8 * 16 + c) * 16 + o];
        r1  += cs1 * th1[(0 * 16 + c) * 16 + o]
             + rs2 * th1[(3 * 16 + c) * 16 + o]
             + vb1 * th1[(6 * 16 + c) * 16 + o];
        c1a += cs2 * th1[(4 * 16 + c) * 16 + o]
             + vb2 * th1[(8 * 16 + c) * 16 + o];
        k1  += sW1 * th1[(1 * 16 + c) * 16 + o] + sW2 * th1[(5 * 16 + c) * 16 + o]
             + sb1 * th1[(7 * 16 + c) * 16 + o] + sb2 * th1[(9 * 16 + c) * 16 + o];
        o2  += cs1 * th2[(0 * 16 + c) * 16 + o]
             + rs2 * th2[(2 * 16 + c) * 16 + o]
             + vb1 * th2[(4 * 16 + c) * 16 + o];
        k2  += sW1 * th2[(1 * 16 + c) * 16 + o] + sW2 * th2[(3 * 16 + c) * 16 + o]
             + sb1 * th2[(5 * 16 + c) * 16 + o] + sb2 * th2[(6 * 16 + c) * 16 + o];
        o3  += cs2 * th3[(1 * 16 + c) * 16 + o]
             + vb2 * th3[(4 * 16 + c) * 16 + o];
        k3  += sW1 * th3[(0 * 16 + c) * 16 + o] + sW2 * th3[(2 * 16 + c) * 16 + o]
             + sb1 * th3[(3 * 16 + c) * 16 + o] + sb2 * th3[(5 * 16 + c) * 16 + o];
    }
    int gt = i * 16 + o;
    R0[gt]   = r0;
    C0[gt]   = c0a + k0 + bias0[o];
    R1[gt]   = r1;
    C1[gt]   = c1a + k1 + bias1[o];
    out2[gt] = o2 + k2 + bias2[o];
    out3[gt] = o3 + k3 + bias3[o];
}

// ---------------------------------------------------------------------------
// k_main v2: streaming pass with LDS-staged CONTIGUOUS global I/O.
//   out[i,j,:] = W[i,j,:]·θ + R[i] + C[j]
// Stage-in: 4 contiguous 1KB-per-wave loads -> LDS (pitch-5 f4, 2/bank free).
// Compute from LDS; write acc back to LDS; contiguous stores.
// ---------------------------------------------------------------------------
__global__ __launch_bounds__(256) void k_main(const float* __restrict__ W1,
                                              const float* __restrict__ W2,
                                              const float* __restrict__ R0,
                                              const float* __restrict__ C0,
                                              const float* __restrict__ R1,
                                              const float* __restrict__ C1,
                                              const float* __restrict__ th0,
                                              const float* __restrict__ th1,
                                              float* __restrict__ out0,
                                              float* __restrict__ out1) {
    int z = blockIdx.z;
    const float* W  = z ? W2 : W1;
    const float* R  = z ? R1 : R0;
    const float* Cc = z ? C1 : C0;
    const float* TH = z ? th1 : th0;
    float* out      = z ? out1 : out0;

    int t  = threadIdx.x;
    int i  = blockIdx.y;
    int jb = blockIdx.x * 256;

    __shared__ float4 xs[1280];       // idx = 5*j_local + k  (20.5 KB)
    __shared__ float  th[256];
    __shared__ float  r[16];
    th[t] = TH[t];
    if (t < 16) r[t] = R[i * 16 + t];

    const float4* Wf4 = (const float4*)W + (size_t)i * 4096 + jb * 4;
    float4*       Of4 = (float4*)out    + (size_t)i * 4096 + jb * 4;

#pragma unroll
    for (int q = 0; q < 4; ++q) {     // contiguous 1KB/wave-instr loads
        int g = t + 256 * q;
        xs[5 * (g >> 2) + (g & 3)] = Wf4[g];
    }
    __syncthreads();

    float x[16];
#pragma unroll
    for (int k = 0; k < 4; ++k) {
        float4 v = xs[5 * t + k];
        x[4 * k] = v.x; x[4 * k + 1] = v.y; x[4 * k + 2] = v.z; x[4 * k + 3] = v.w;
    }
    const float4* cj = (const float4*)(Cc + (jb + t) * 16);
    float4 c0 = cj[0], c1 = cj[1], c2 = cj[2], c3 = cj[3];
    float acc[16] = {c0.x, c0.y, c0.z, c0.w, c1.x, c1.y, c1.z, c1.w,
                     c2.x, c2.y, c2.z, c2.w, c3.x, c3.y, c3.z, c3.w};
#pragma unroll
    for (int o = 0; o < 16; ++o) acc[o] += r[o];
#pragma unroll
    for (int c = 0; c < 16; ++c) {
        float xv = x[c];
#pragma unroll
        for (int o = 0; o < 16; ++o) acc[o] += xv * th[c * 16 + o];
    }
    __syncthreads();                  // all xs reads done
#pragma unroll
    for (int k = 0; k < 4; ++k)
        xs[5 * t + k] = make_float4(acc[4 * k], acc[4 * k + 1],
                                    acc[4 * k + 2], acc[4 * k + 3]);
    __syncthreads();
#pragma unroll
    for (int q = 0; q < 4; ++q) {     // contiguous stores
        int g = t + 256 * q;
        Of4[g] = xs[5 * (g >> 2) + (g & 3)];
    }
}

extern "C" void kernel_launch(void* const* d_in, const int* in_sizes, int n_in,
                              void* d_out, int out_size, void* d_ws, size_t ws_size,
                              hipStream_t stream) {
    // input order (interleaved theta/bias):
    // 0:W1 1:W2 2:b1 3:b2 4:theta_0 5:bias_0 6:theta_1 7:bias_1
    // 8:theta_2 9:bias_2 10:theta_3 11:bias_3
    const float* W1    = (const float*)d_in[0];
    const float* W2    = (const float*)d_in[1];
    const float* b1    = (const float*)d_in[2];
    const float* b2    = (const float*)d_in[3];
    const float* th0   = (const float*)d_in[4];
    const float* bias0 = (const float*)d_in[5];
    const float* th1   = (const float*)d_in[6];
    const float* bias1 = (const float*)d_in[7];
    const float* th2   = (const float*)d_in[8];
    const float* bias2 = (const float*)d_in[9];
    const float* th3   = (const float*)d_in[10];
    const float* bias3 = (const float*)d_in[11];

    float* out  = (float*)d_out;
    float* out0 = out;
    float* out1 = out + (size_t)NDIM * NDIM * CH;
    float* out2 = out1 + (size_t)NDIM * NDIM * CH;
    float* out3 = out2 + (size_t)NDIM * CH;

    // scratch in the (not-yet-written) out0 region (19.1 MB of 64 MB):
    float* rowpart = out0;                       // [2][16][1024][16]  = 524288
    float* colpart = out0 + 524288;              // [2][128][1024][16] = 4194304
    float* tiletot = out0 + 4718592;             // [2][2048][16]      = 65536

    // workspace: 65,536 floats = 262,144 B (well under proven budget)
    float* ws = (float*)d_ws;
    float* R0 = ws;                              // 16384 each
    float* C0 = R0 + 16384;
    float* R1 = C0 + 16384;
    float* C1 = R1 + 16384;

    k_fused<<<dim3(16, 128, 2), dim3(256), 0, stream>>>(W1, W2, rowpart, colpart, tiletot);
    k_mid<<<dim3(64), dim3(256), 0, stream>>>(rowpart, colpart, tiletot, b1, b2,
                                              th0, th1, th2, th3,
                                              bias0, bias1, bias2, bias3,
                                              R0, C0, R1, C1, out2, out3);
    k_main<<<dim3(4, NDIM, 2), dim3(256), 0, stream>>>(W1, W2, R0, C0, R1, C1,
                                                       th0, th1 + 2 * 256,
                                                       out0, out1);
}

// Round 8
// 89.934 us; speedup vs baseline: 1.8149x; 1.8149x over previous
//
#include <hip/hip_runtime.h>

#define NDIM 1024
#define CH 16
#define ROW_F4 4096   // float4 per W row (1024*16/4)

__device__ inline float4 f4add(float4 a, float4 b) {
    return make_float4(a.x + b.x, a.y + b.y, a.z + b.z, a.w + b.w);
}
__device__ inline float4 f4zero() { return make_float4(0.f, 0.f, 0.f, 0.f); }

// ---------------------------------------------------------------------------
// k_fused: ONE pass over W -> row partials (16 j-chunks), col partials
// (128 i-chunks), and per-tile totals. Block = 8 rows x 64 cols.
// LDS = 8x258 float4 (33 KB) -> 4 blocks/CU. Partials live in out0 scratch.
// ---------------------------------------------------------------------------
__global__ __launch_bounds__(256) void k_fused(const float* __restrict__ W1,
                                               const float* __restrict__ W2,
                                               float* __restrict__ rowpart,
                                               float* __restrict__ colpart,
                                               float* __restrict__ tiletot) {
    int t  = threadIdx.x;
    int jt = blockIdx.x, it = blockIdx.y, z = blockIdx.z;
    const float4* base = (const float4*)(z ? W2 : W1)
                       + (size_t)it * 8 * ROW_F4 + jt * 256 + t;
    __shared__ float4 tile[8][258];
    __shared__ float4 rtot[32];
    float4 colacc = f4zero();
#pragma unroll
    for (int r = 0; r < 8; ++r) {
        float4 v = base[(size_t)r * ROW_F4];
        colacc = f4add(colacc, v);
        tile[r][t] = v;
    }
    ((float4*)colpart)[(size_t)(z * 128 + it) * 4096 + jt * 256 + t] = colacc;
    __syncthreads();
    if (t < 32) {   // row partials: r = t>>2, cq = t&3
        int r = t >> 2, cq = t & 3;
        float4 s = f4zero();
#pragma unroll
        for (int jl = 0; jl < 64; ++jl) s = f4add(s, tile[r][jl * 4 + cq]);
        ((float4*)rowpart)[(size_t)(z * 16 + jt) * 4096 + (it * 8 + r) * 4 + cq] = s;
        rtot[t] = s;
    }
    __syncthreads();
    if (t < 4) {    // tile total (16 ch)
        float4 s = f4zero();
#pragma unroll
        for (int r = 0; r < 8; ++r) s = f4add(s, rtot[r * 4 + t]);
        ((float4*)tiletot)[(size_t)(z * 2048 + it * 16 + jt) * 4 + t] = s;
    }
}

// ---------------------------------------------------------------------------
// k_reduce: parallel, coalesced reduction of all partials. 163 blocks:
//   0..127 : col chunks (128) -> colsumF. 64 f4 outputs/block, 4-way chunk
//            split per output (32 loads/thread) + LDS combine.
//   128..159: row chunks (16) -> rowsumF. 256 f4 outputs/block, 1 thr each.
//   160    : global W sums from tiletot (128 thr/tensor + LDS tree).
//   161,162: b1 / b2 sums.
// ---------------------------------------------------------------------------
__global__ __launch_bounds__(256) void k_reduce(const float* __restrict__ rowpart,
                                                const float* __restrict__ colpart,
                                                const float* __restrict__ tiletot,
                                                const float* __restrict__ b1,
                                                const float* __restrict__ b2,
                                                float* __restrict__ rowsumF,
                                                float* __restrict__ colsumF,
                                                float* __restrict__ sums) {
    int t = threadIdx.x;
    int b = blockIdx.x;
    if (b < 128) {
        const float4* cp = (const float4*)colpart;
        int o = b * 64 + (t & 63);      // f4 output id, 0..8191
        int p = t >> 6;                 // 4-way chunk split
        int z = o >> 12, rem = o & 4095;
        float4 s = f4zero();
#pragma unroll 8
        for (int k = 0; k < 32; ++k)
            s = f4add(s, cp[(size_t)(z * 128 + p * 32 + k) * 4096 + rem]);
        __shared__ float4 lds[256];
        lds[t] = s;
        __syncthreads();
        if (t < 64) {
            float4 r = f4add(f4add(lds[t], lds[t + 64]),
                             f4add(lds[t + 128], lds[t + 192]));
            ((float4*)colsumF)[o] = r;
        }
    } else if (b < 160) {
        const float4* rp = (const float4*)rowpart;
        int o = (b - 128) * 256 + t;    // 0..8191
        int z = o >> 12, rem = o & 4095;
        float4 s = f4zero();
#pragma unroll
        for (int k = 0; k < 16; ++k)
            s = f4add(s, rp[(size_t)(z * 16 + k) * 4096 + rem]);
        ((float4*)rowsumF)[o] = s;
    } else if (b == 160) {
        int c = t & 15, p = (t >> 4) & 7, z = t >> 7;
        float s = 0.f;
#pragma unroll 8
        for (int m = 0; m < 256; ++m)
            s += tiletot[(size_t)(z * 2048 + p * 256 + m) * 16 + c];
        __shared__ float ldsA[2][8][16];
        ldsA[z][p][c] = s;
        __syncthreads();
        if (t < 32) {
            int zz = t >> 4, cc = t & 15;
            float r = 0.f;
#pragma unroll
            for (int q = 0; q < 8; ++q) r += ldsA[zz][q][cc];
            sums[zz * 16 + cc] = r;
        }
    } else {
        int w = b - 161;                // 0: b1, 1: b2
        const float* src = w ? b2 : b1;
        int c = t & 15, p = t >> 4;
        float s = 0.f;
#pragma unroll 8
        for (int m = 0; m < 64; ++m)
            s += src[(size_t)(p * 64 + m) * 16 + c];
        __shared__ float ldsB[16][16];
        ldsB[p][c] = s;
        __syncthreads();
        if (t < 16) {
            float r = 0.f;
#pragma unroll
            for (int q = 0; q < 16; ++q) r += ldsB[q][t];
            sums[32 + w * 16 + t] = r;
        }
    }
}

// ---------------------------------------------------------------------------
// k_smalls: all O(N) outputs from finalized sums. Thread -> (i, o).
//   R0[i][o] = rsW1[i]·θ0_1
//   C0[j][o] = csW1[j]·θ0_2 + rsW2[j]·θ0_4 + b1[j]·θ0_6 + const0 + bias0
//   R1[i][o] = csW1[i]·θ1_0 + rsW2[i]·θ1_3 + b1[i]·θ1_6
//   C1[j][o] = csW2[j]·θ1_4 + b2[j]·θ1_8 + const1 + bias1
//   out2/out3 with constants folded. theta [k][c][o] at k*256 + c*16 + o
// ---------------------------------------------------------------------------
__global__ __launch_bounds__(256) void k_smalls(const float* __restrict__ rowsum,
                                                const float* __restrict__ colsum,
                                                const float* __restrict__ sums,
                                                const float* __restrict__ b1,
                                                const float* __restrict__ b2,
                                                const float* __restrict__ th0,
                                                const float* __restrict__ th1,
                                                const float* __restrict__ th2,
                                                const float* __restrict__ th3,
                                                const float* __restrict__ bias0,
                                                const float* __restrict__ bias1,
                                                const float* __restrict__ bias2,
                                                const float* __restrict__ bias3,
                                                float* __restrict__ R0, float* __restrict__ C0,
                                                float* __restrict__ R1, float* __restrict__ C1,
                                                float* __restrict__ out2, float* __restrict__ out3) {
    int gt = blockIdx.x * 256 + threadIdx.x;
    int i = gt >> 4, o = gt & 15;
    const float* rs1 = rowsum + i * 16;
    const float* rs2 = rowsum + 16384 + i * 16;
    const float* cs1 = colsum + i * 16;
    const float* cs2 = colsum + 16384 + i * 16;
    const float* b1i = b1 + i * 16;
    const float* b2i = b2 + i * 16;
    float r0 = 0.f, c0a = 0.f, r1 = 0.f, c1a = 0.f, o2 = 0.f, o3 = 0.f;
    float k0 = 0.f, k1 = 0.f, k2 = 0.f, k3 = 0.f;
#pragma unroll
    for (int c = 0; c < 16; ++c) {
        float sW1 = sums[c], sW2 = sums[16 + c], sb1 = sums[32 + c], sb2 = sums[48 + c];
        r0  += rs1[c] * th0[(1 * 16 + c) * 16 + o];
        c0a += cs1[c] * th0[(2 * 16 + c) * 16 + o]
             + rs2[c] * th0[(4 * 16 + c) * 16 + o]
             + b1i[c] * th0[(6 * 16 + c) * 16 + o];
        k0  += sW1 * th0[(3 * 16 + c) * 16 + o] + sW2 * th0[(5 * 16 + c) * 16 + o]
             + sb1 * th0[(7 * 16 + c) * 16 + o] + sb2 * th0[(8 * 16 + c) * 16 + o];
        r1  += cs1[c] * th1[(0 * 16 + c) * 16 + o]
             + rs2[c] * th1[(3 * 16 + c) * 16 + o]
             + b1i[c] * th1[(6 * 16 + c) * 16 + o];
        c1a += cs2[c] * th1[(4 * 16 + c) * 16 + o]
             + b2i[c] * th1[(8 * 16 + c) * 16 + o];
        k1  += sW1 * th1[(1 * 16 + c) * 16 + o] + sW2 * th1[(5 * 16 + c) * 16 + o]
             + sb1 * th1[(7 * 16 + c) * 16 + o] + sb2 * th1[(9 * 16 + c) * 16 + o];
        o2  += cs1[c] * th2[(0 * 16 + c) * 16 + o]
             + rs2[c] * th2[(2 * 16 + c) * 16 + o]
             + b1i[c] * th2[(4 * 16 + c) * 16 + o];
        k2  += sW1 * th2[(1 * 16 + c) * 16 + o] + sW2 * th2[(3 * 16 + c) * 16 + o]
             + sb1 * th2[(5 * 16 + c) * 16 + o] + sb2 * th2[(6 * 16 + c) * 16 + o];
        o3  += cs2[c] * th3[(1 * 16 + c) * 16 + o]
             + b2i[c] * th3[(4 * 16 + c) * 16 + o];
        k3  += sW1 * th3[(0 * 16 + c) * 16 + o] + sW2 * th3[(2 * 16 + c) * 16 + o]
             + sb1 * th3[(3 * 16 + c) * 16 + o] + sb2 * th3[(5 * 16 + c) * 16 + o];
    }
    R0[gt]   = r0;
    C0[gt]   = c0a + k0 + bias0[o];
    R1[gt]   = r1;
    C1[gt]   = c1a + k1 + bias1[o];
    out2[gt] = o2 + k2 + bias2[o];
    out3[gt] = o3 + k3 + bias3[o];
}

// ---------------------------------------------------------------------------
// k_main: streaming pass with LDS-staged CONTIGUOUS global I/O.
//   out[i,j,:] = W[i,j,:]·θ + R[i] + C[j]
// ---------------------------------------------------------------------------
__global__ __launch_bounds__(256) void k_main(const float* __restrict__ W1,
                                              const float* __restrict__ W2,
                                              const float* __restrict__ R0,
                                              const float* __restrict__ C0,
                                              const float* __restrict__ R1,
                                              const float* __restrict__ C1,
                                              const float* __restrict__ th0,
                                              const float* __restrict__ th1,
                                              float* __restrict__ out0,
                                              float* __restrict__ out1) {
    int z = blockIdx.z;
    const float* W  = z ? W2 : W1;
    const float* R  = z ? R1 : R0;
    const float* Cc = z ? C1 : C0;
    const float* TH = z ? th1 : th0;
    float* out      = z ? out1 : out0;

    int t  = threadIdx.x;
    int i  = blockIdx.y;
    int jb = blockIdx.x * 256;

    __shared__ float4 xs[1280];       // idx = 5*j_local + k
    __shared__ float  th[256];
    __shared__ float  r[16];
    th[t] = TH[t];
    if (t < 16) r[t] = R[i * 16 + t];

    const float4* Wf4 = (const float4*)W + (size_t)i * 4096 + jb * 4;
    float4*       Of4 = (float4*)out    + (size_t)i * 4096 + jb * 4;

#pragma unroll
    for (int q = 0; q < 4; ++q) {
        int g = t + 256 * q;
        xs[5 * (g >> 2) + (g & 3)] = Wf4[g];
    }
    __syncthreads();

    float x[16];
#pragma unroll
    for (int k = 0; k < 4; ++k) {
        float4 v = xs[5 * t + k];
        x[4 * k] = v.x; x[4 * k + 1] = v.y; x[4 * k + 2] = v.z; x[4 * k + 3] = v.w;
    }
    const float4* cj = (const float4*)(Cc + (jb + t) * 16);
    float4 c0 = cj[0], c1 = cj[1], c2 = cj[2], c3 = cj[3];
    float acc[16] = {c0.x, c0.y, c0.z, c0.w, c1.x, c1.y, c1.z, c1.w,
                     c2.x, c2.y, c2.z, c2.w, c3.x, c3.y, c3.z, c3.w};
#pragma unroll
    for (int o = 0; o < 16; ++o) acc[o] += r[o];
#pragma unroll
    for (int c = 0; c < 16; ++c) {
        float xv = x[c];
#pragma unroll
        for (int o = 0; o < 16; ++o) acc[o] += xv * th[c * 16 + o];
    }
    __syncthreads();
#pragma unroll
    for (int k = 0; k < 4; ++k)
        xs[5 * t + k] = make_float4(acc[4 * k], acc[4 * k + 1],
                                    acc[4 * k + 2], acc[4 * k + 3]);
    __syncthreads();
#pragma unroll
    for (int q = 0; q < 4; ++q) {
        int g = t + 256 * q;
        Of4[g] = xs[5 * (g >> 2) + (g & 3)];
    }
}

extern "C" void kernel_launch(void* const* d_in, const int* in_sizes, int n_in,
                              void* d_out, int out_size, void* d_ws, size_t ws_size,
                              hipStream_t stream) {
    // input order (interleaved theta/bias):
    // 0:W1 1:W2 2:b1 3:b2 4:theta_0 5:bias_0 6:theta_1 7:bias_1
    // 8:theta_2 9:bias_2 10:theta_3 11:bias_3
    const float* W1    = (const float*)d_in[0];
    const float* W2    = (const float*)d_in[1];
    const float* b1    = (const float*)d_in[2];
    const float* b2    = (const float*)d_in[3];
    const float* th0   = (const float*)d_in[4];
    const float* bias0 = (const float*)d_in[5];
    const float* th1   = (const float*)d_in[6];
    const float* bias1 = (const float*)d_in[7];
    const float* th2   = (const float*)d_in[8];
    const float* bias2 = (const float*)d_in[9];
    const float* th3   = (const float*)d_in[10];
    const float* bias3 = (const float*)d_in[11];

    float* out  = (float*)d_out;
    float* out0 = out;
    float* out1 = out + (size_t)NDIM * NDIM * CH;
    float* out2 = out1 + (size_t)NDIM * NDIM * CH;
    float* out3 = out2 + (size_t)NDIM * CH;

    // scratch in the (not-yet-written) out0 region (19.1 MB of 64 MB):
    float* rowpart = out0;                       // [2][16][1024][16]  = 524288
    float* colpart = out0 + 524288;              // [2][128][1024][16] = 4194304
    float* tiletot = out0 + 4718592;             // [2][2048][16]      = 65536

    // workspace: 131,136 floats = 524,544 B (≤ proven budget)
    float* ws      = (float*)d_ws;
    float* rowsumF = ws;                         // [2][1024][16] = 32768
    float* colsumF = ws + 32768;                 // [2][1024][16] = 32768
    float* sums    = ws + 65536;                 // [4][16] = 64
    float* R0      = ws + 65600;                 // 16384 each
    float* C0      = R0 + 16384;
    float* R1      = C0 + 16384;
    float* C1      = R1 + 16384;

    k_fused<<<dim3(16, 128, 2), dim3(256), 0, stream>>>(W1, W2, rowpart, colpart, tiletot);
    k_reduce<<<dim3(163), dim3(256), 0, stream>>>(rowpart, colpart, tiletot, b1, b2,
                                                  rowsumF, colsumF, sums);
    k_smalls<<<dim3(64), dim3(256), 0, stream>>>(rowsumF, colsumF, sums, b1, b2,
                                                 th0, th1, th2, th3,
                                                 bias0, bias1, bias2, bias3,
                                                 R0, C0, R1, C1, out2, out3);
    k_main<<<dim3(4, NDIM, 2), dim3(256), 0, stream>>>(W1, W2, R0, C0, R1, C1,
                                                       th0, th1 + 2 * 256,
                                                       out0, out1);
}